// Round 8
// baseline (652.749 us; speedup 1.0000x reference)
//
#include <hip/hip_runtime.h>

#define NB 8
#define NC 256
#define NHW 1024   // H*W
#define NL 4
#define NG 4
#define NK 2048
#define ND 64      // C/G

#define RS 68      // r_lds row stride (floats)
#define CS 72      // (fallback kernel) codebook LDS row stride (halfs)

typedef __attribute__((ext_vector_type(8)))  _Float16 f16x8;
typedef __attribute__((ext_vector_type(4)))  _Float16 f16x4;
typedef __attribute__((ext_vector_type(4)))  float    f32x4;
typedef __attribute__((ext_vector_type(16))) float    f32x16;

// fp16 hi/lo split: v = h + l + O(2^-24 v). Products h*h etc are exact in fp32.
__device__ __forceinline__ void fsplit(float v, _Float16& h, _Float16& l) {
    _Float16 hh = (_Float16)v;
    h = hh;
    l = (_Float16)(v - (float)hh);
}

// ---------------- fast path: prep kernel (32x32x16 fragments) ----------------
// Per 32-codeword tile: 8 fragments [hiC0..hiC3, loC0..loC3], each 64 lanes x
// 8 halfs, lane-linear. B layout for mfma_32x32x16: col = lane&31,
// d(k-dim) = c*16 + (lane>>5)*8 + j. Fused cn = 0.5*||c||^2 (exact fp32).
__global__ void cq_prep32_kernel(const float* __restrict__ cb,
                                 _Float16* __restrict__ wfrag,
                                 float* __restrict__ cn) {
    int wv   = (blockIdx.x * 256 + threadIdx.x) >> 6;  // tile id 0..1023
    int lane = threadIdx.x & 63;
    int col  = lane & 31, half = lane >> 5;
    int lg   = wv >> 6, kt = wv & 63;
    int k    = kt * 32 + col;
    const float* src = cb + ((size_t)lg * NK + k) * ND + half * 8;
    _Float16* outp = wfrag + (size_t)wv * 4096;   // tile = 8192 B = 4096 halfs

    float s = 0.f;
#pragma unroll
    for (int c = 0; c < 4; ++c) {
        float4 v0 = *(const float4*)(src + c * 16);
        float4 v1 = *(const float4*)(src + c * 16 + 4);
        f16x8 hv, lv; _Float16 h, lo;
        fsplit(v0.x,h,lo); hv[0]=h; lv[0]=lo;
        fsplit(v0.y,h,lo); hv[1]=h; lv[1]=lo;
        fsplit(v0.z,h,lo); hv[2]=h; lv[2]=lo;
        fsplit(v0.w,h,lo); hv[3]=h; lv[3]=lo;
        fsplit(v1.x,h,lo); hv[4]=h; lv[4]=lo;
        fsplit(v1.y,h,lo); hv[5]=h; lv[5]=lo;
        fsplit(v1.z,h,lo); hv[6]=h; lv[6]=lo;
        fsplit(v1.w,h,lo); hv[7]=h; lv[7]=lo;
        *(f16x8*)(outp +        c * 512 + lane * 8) = hv;
        *(f16x8*)(outp + 2048 + c * 512 + lane * 8) = lv;
        s += v0.x*v0.x + v0.y*v0.y + v0.z*v0.z + v0.w*v0.w
           + v1.x*v1.x + v1.y*v1.y + v1.z*v1.z + v1.w*v1.w;
    }
    s += __shfl_xor(s, 32, 64);
    if (half == 0) cn[(size_t)lg * NK + k] = 0.5f * s;
}

// ---------------- fast path: main kernel v8 (32x32x16) ----------------
// 1024 blocks x 256 threads. Block owns 32 rows; each wave owns a k-quarter
// (512 cw = 16 stages of 32). X/Y register double-buffer with
// sched_barrier(0) pinning loads before the MFMA block (anti-sink).
__global__ __launch_bounds__(256, 2) void cq_main8_kernel(
    const float* __restrict__ x, const float* __restrict__ cb,
    const _Float16* __restrict__ wfrag, const float* __restrict__ cn,
    float* __restrict__ out)
{
    __shared__ float r_lds[32][RS];
    __shared__ float mv_lds[4][32];
    __shared__ int   mi_lds[4][32];
    __shared__ int   ks_lds[32];

    const int tid = threadIdx.x;
    // bijective XCD swizzle (1024 = 8 XCD * 128)
    const int blk = (blockIdx.x & 7) * 128 + (blockIdx.x >> 3);
    const int nt  = blk & 31;
    const int g   = (blk >> 5) & 3;
    const int b   = blk >> 7;
    const int n0  = nt * 32;

    const float* xb = x + ((size_t)(b * NC + g * ND)) * NHW + n0;
#pragma unroll
    for (int dd = 0; dd < 2; ++dd) {
        int d = (tid >> 3) + dd * 32;
        int n = (tid & 7) * 4;
        float4 xv = *(const float4*)(&xb[(size_t)d * NHW + n]);
        r_lds[n + 0][d] = xv.x; r_lds[n + 1][d] = xv.y;
        r_lds[n + 2][d] = xv.z; r_lds[n + 3][d] = xv.w;
    }
    __syncthreads();

    const int lane = tid & 63;
    const int kq   = tid >> 6;        // k-quarter (4 waves)
    const int col  = lane & 31;
    const int half = lane >> 5;
    const int kbase = kq * 512;

    for (int l = 0; l < NL; ++l) {
        const float* cbl_g = cb + (size_t)(l * NG + g) * NK * ND;
        const float* cnl   = cn + (size_t)(l * NG + g) * NK;
        const _Float16* fb = wfrag + ((size_t)((l * NG + g) * 64 + kq * 16)) * 4096;

        // negated hi/lo A fragments: row = lane&31, d = c*16 + half*8 + j
        f16x8 ah[4], al[4];
#pragma unroll
        for (int c = 0; c < 4; ++c) {
            const float* rp = &r_lds[col][c * 16 + half * 8];
            float4 v0 = *(const float4*)(rp);
            float4 v1 = *(const float4*)(rp + 4);
            f16x8 hv, lv; _Float16 h, lo;
            fsplit(-v0.x,h,lo); hv[0]=h; lv[0]=lo;
            fsplit(-v0.y,h,lo); hv[1]=h; lv[1]=lo;
            fsplit(-v0.z,h,lo); hv[2]=h; lv[2]=lo;
            fsplit(-v0.w,h,lo); hv[3]=h; lv[3]=lo;
            fsplit(-v1.x,h,lo); hv[4]=h; lv[4]=lo;
            fsplit(-v1.y,h,lo); hv[5]=h; lv[5]=lo;
            fsplit(-v1.z,h,lo); hv[6]=h; lv[6]=lo;
            fsplit(-v1.w,h,lo); hv[7]=h; lv[7]=lo;
            ah[c] = hv; al[c] = lv;
        }

        float minv[16];
        int   mini[16];
#pragma unroll
        for (int j = 0; j < 16; ++j) { minv[j] = 3.4e38f; mini[j] = 0; }

        f16x8 Xh[4], Xl[4], Yh[4], Yl[4];
        float cvX, cvY;

        auto LD = [&](f16x8 (&H)[4], f16x8 (&L)[4], float& cv, int s) {
            const _Float16* p = fb + (size_t)s * 4096 + lane * 8;
            H[0] = *(const f16x8*)(p);
            H[1] = *(const f16x8*)(p + 512);
            H[2] = *(const f16x8*)(p + 1024);
            H[3] = *(const f16x8*)(p + 1536);
            L[0] = *(const f16x8*)(p + 2048);
            L[1] = *(const f16x8*)(p + 2560);
            L[2] = *(const f16x8*)(p + 3072);
            L[3] = *(const f16x8*)(p + 3584);
            cv = cnl[kbase + s * 32 + col];
        };

        auto ST = [&](const f16x8 (&H)[4], const f16x8 (&L)[4], float cv, int s) {
            f32x16 acc;
#pragma unroll
            for (int j = 0; j < 16; ++j) acc[j] = cv;   // score = cv - r.c
#pragma unroll
            for (int c = 0; c < 4; ++c)
                acc = __builtin_amdgcn_mfma_f32_32x32x16_f16(ah[c], H[c], acc, 0, 0, 0);
#pragma unroll
            for (int c = 0; c < 4; ++c)
                acc = __builtin_amdgcn_mfma_f32_32x32x16_f16(ah[c], L[c], acc, 0, 0, 0);
#pragma unroll
            for (int c = 0; c < 4; ++c)
                acc = __builtin_amdgcn_mfma_f32_32x32x16_f16(al[c], H[c], acc, 0, 0, 0);
#pragma unroll
            for (int j = 0; j < 16; ++j) {     // s is compile-time (unrolled)
                bool lt = acc[j] < minv[j];
                minv[j] = lt ? acc[j] : minv[j];
                mini[j] = lt ? s : mini[j];
            }
        };

        LD(Xh, Xl, cvX, 0);
#pragma unroll
        for (int i = 0; i < 8; ++i) {
            LD(Yh, Yl, cvY, 2 * i + 1);
            __builtin_amdgcn_sched_barrier(0);   // pin loads above MFMAs
            ST(Xh, Xl, cvX, 2 * i);
            if (i < 7) LD(Xh, Xl, cvX, 2 * i + 2);
            __builtin_amdgcn_sched_barrier(0);
            ST(Yh, Yl, cvY, 2 * i + 1);
        }

        // reconstruct k; reduce over the 32 cols within each half-wave.
        // Explicit lower-k tie-break (exact fp32 ties do occur).
        int kk[16];
#pragma unroll
        for (int j = 0; j < 16; ++j) kk[j] = kbase + mini[j] * 32 + col;
#pragma unroll
        for (int m = 1; m <= 16; m <<= 1) {
#pragma unroll
            for (int j = 0; j < 16; ++j) {
                float ov = __shfl_xor(minv[j], m, 64);
                int   oi = __shfl_xor(kk[j], m, 64);
                if (ov < minv[j] || (ov == minv[j] && oi < kk[j])) {
                    minv[j] = ov; kk[j] = oi;
                }
            }
        }
        if (col == 0) {
#pragma unroll
            for (int j = 0; j < 16; ++j) {
                int row = (j & 3) + 8 * (j >> 2) + 4 * half;  // 32x32 C/D map
                mv_lds[kq][row] = minv[j];
                mi_lds[kq][row] = kk[j];
            }
        }
        __syncthreads();
        if (tid < 32) {   // combine 4 quarters ascending (tie -> lower k)
            float bv = mv_lds[0][tid]; int bi = mi_lds[0][tid];
#pragma unroll
            for (int q = 1; q < 4; ++q) {
                float v = mv_lds[q][tid];
                if (v < bv) { bv = v; bi = mi_lds[q][tid]; }
            }
            ks_lds[tid] = bi;
        }
        __syncthreads();

        // r -= cb[k*]  (exact fp32, rows L2-hot)
        {
            int row = tid >> 3, dc = (tid & 7) * 8;
            int kw = ks_lds[row];
            const float* qp = cbl_g + (size_t)kw * ND + dc;
#pragma unroll
            for (int i = 0; i < 2; ++i) {
                float4 q  = *(const float4*)(qp + i * 4);
                float* rp = &r_lds[row][dc + i * 4];
                float4 rv = *(float4*)rp;
                rv.x -= q.x; rv.y -= q.y; rv.z -= q.z; rv.w -= q.w;
                *(float4*)rp = rv;
            }
        }
        __syncthreads();
    }

    // out = x - r_final
    float* ob = out + ((size_t)(b * NC + g * ND)) * NHW + n0;
#pragma unroll
    for (int dd = 0; dd < 2; ++dd) {
        int d = (tid >> 3) + dd * 32;
        int n = (tid & 7) * 4;
        float4 xv = *(const float4*)(&xb[(size_t)d * NHW + n]);
        float4 ov;
        ov.x = xv.x - r_lds[n + 0][d];
        ov.y = xv.y - r_lds[n + 1][d];
        ov.z = xv.z - r_lds[n + 2][d];
        ov.w = xv.w - r_lds[n + 3][d];
        *(float4*)(&ob[(size_t)d * NHW + n]) = ov;
    }
}

// ---------------- fallback path (round-2 kernels, 128 KB ws) ----------------
__global__ void cq_cnorm_kernel(const float* __restrict__ cb, float* __restrict__ cn) {
    int idx = blockIdx.x * 256 + threadIdx.x;
    const float4* p = reinterpret_cast<const float4*>(cb + (size_t)idx * ND);
    float s = 0.f;
#pragma unroll
    for (int i = 0; i < ND / 4; ++i) {
        float4 v = p[i];
        s += v.x * v.x + v.y * v.y + v.z * v.z + v.w * v.w;
    }
    cn[idx] = 0.5f * s;
}

__global__ __launch_bounds__(256, 1) void cq_main_kernel(
    const float* __restrict__ x, const float* __restrict__ cb,
    const float* __restrict__ cn, float* __restrict__ out)
{
    __shared__ float    r_lds[128][RS];
    __shared__ _Float16 cbh_lds[2][128][CS];
    __shared__ _Float16 cbl_lds[2][128][CS];
    __shared__ float    mv_lds[2][128];
    __shared__ int      mi_lds[2][128];
    __shared__ int      ks_lds[128];

    const int tid = threadIdx.x;
    const int blk = blockIdx.x;
    const int nt  = blk & 7;
    const int bg  = blk >> 3;
    const int g   = bg & 3;
    const int b   = bg >> 2;
    const int n0  = nt * 128;

    const float* xb = x + ((size_t)(b * NC + g * ND)) * NHW + n0;
#pragma unroll
    for (int dd = 0; dd < 8; ++dd) {
        int d = (tid >> 5) + dd * 8;
        int n = (tid & 31) * 4;
        float4 xv = *reinterpret_cast<const float4*>(&xb[(size_t)d * NHW + n]);
        r_lds[n + 0][d] = xv.x; r_lds[n + 1][d] = xv.y;
        r_lds[n + 2][d] = xv.z; r_lds[n + 3][d] = xv.w;
    }

    const int lane = tid & 63;
    const int wid  = tid >> 6;
    const int rg   = wid & 1;
    const int kh   = wid >> 1;
    const int l4   = lane & 15;
    const int l16  = lane >> 4;

    __syncthreads();

    for (int l = 0; l < NL; ++l) {
        const float* cbl_g = cb + (size_t)(l * NG + g) * NK * ND;
        const float* cnl   = cn + (size_t)(l * NG + g) * NK;

        f16x8 ah[4][2], al[4][2];
#pragma unroll
        for (int ns = 0; ns < 4; ++ns) {
#pragma unroll
            for (int c = 0; c < 2; ++c) {
                const float* rp = &r_lds[rg * 64 + ns * 16 + l4][c * 32 + l16 * 8];
                float4 v0 = *reinterpret_cast<const float4*>(rp);
                float4 v1 = *reinterpret_cast<const float4*>(rp + 4);
                _Float16 h, lo; f16x8 hv, lv;
                fsplit(-v0.x, h, lo); hv[0] = h; lv[0] = lo;
                fsplit(-v0.y, h, lo); hv[1] = h; lv[1] = lo;
                fsplit(-v0.z, h, lo); hv[2] = h; lv[2] = lo;
                fsplit(-v0.w, h, lo); hv[3] = h; lv[3] = lo;
                fsplit(-v1.x, h, lo); hv[4] = h; lv[4] = lo;
                fsplit(-v1.y, h, lo); hv[5] = h; lv[5] = lo;
                fsplit(-v1.z, h, lo); hv[6] = h; lv[6] = lo;
                fsplit(-v1.w, h, lo); hv[7] = h; lv[7] = lo;
                ah[ns][c] = hv; al[ns][c] = lv;
            }
        }

        float minv[4][4];
        int   mini[4][4];
#pragma unroll
        for (int i = 0; i < 4; ++i)
#pragma unroll
            for (int j = 0; j < 4; ++j) { minv[i][j] = 3.4e38f; mini[i][j] = 0; }

        float4 sreg[8];
#pragma unroll
        for (int p = 0; p < 8; ++p) {
            int kk = p * 16 + (tid >> 4);
            int kg = (kk < 64) ? kk : (1024 - 64 + kk);
            sreg[p] = *reinterpret_cast<const float4*>(&cbl_g[(size_t)kg * ND + (tid & 15) * 4]);
        }
#pragma unroll
        for (int p = 0; p < 8; ++p) {
            int kk = p * 16 + (tid >> 4);
            float4 v = sreg[p];
            _Float16 h, lo; f16x4 hv, lv;
            fsplit(v.x, h, lo); hv[0] = h; lv[0] = lo;
            fsplit(v.y, h, lo); hv[1] = h; lv[1] = lo;
            fsplit(v.z, h, lo); hv[2] = h; lv[2] = lo;
            fsplit(v.w, h, lo); hv[3] = h; lv[3] = lo;
            *reinterpret_cast<f16x4*>(&cbh_lds[0][kk][(tid & 15) * 4]) = hv;
            *reinterpret_cast<f16x4*>(&cbl_lds[0][kk][(tid & 15) * 4]) = lv;
        }

        for (int s = 0; s < 16; ++s) {
            __syncthreads();

            if (s < 15) {
#pragma unroll
                for (int p = 0; p < 8; ++p) {
                    int kk = p * 16 + (tid >> 4);
                    int kg = (kk < 64) ? ((s + 1) * 64 + kk) : (1024 + (s + 1) * 64 + (kk - 64));
                    sreg[p] = *reinterpret_cast<const float4*>(&cbl_g[(size_t)kg * ND + (tid & 15) * 4]);
                }
            }

            const int buf = s & 1;
            for (int ks = 0; ks < 4; ++ks) {
                int lrow = kh * 64 + ks * 16 + l4;
                int kabs = kh * 1024 + s * 64 + ks * 16 + l4;
                f16x8 bh0 = *reinterpret_cast<const f16x8*>(&cbh_lds[buf][lrow][l16 * 8]);
                f16x8 bh1 = *reinterpret_cast<const f16x8*>(&cbh_lds[buf][lrow][32 + l16 * 8]);
                f16x8 bl0 = *reinterpret_cast<const f16x8*>(&cbl_lds[buf][lrow][l16 * 8]);
                f16x8 bl1 = *reinterpret_cast<const f16x8*>(&cbl_lds[buf][lrow][32 + l16 * 8]);
                float cnv = cnl[kabs];
                f32x4 acc[4];
#pragma unroll
                for (int ns = 0; ns < 4; ++ns) acc[ns] = (f32x4){cnv, cnv, cnv, cnv};
#pragma unroll
                for (int ns = 0; ns < 4; ++ns) {
                    acc[ns] = __builtin_amdgcn_mfma_f32_16x16x32_f16(ah[ns][0], bh0, acc[ns], 0, 0, 0);
                    acc[ns] = __builtin_amdgcn_mfma_f32_16x16x32_f16(ah[ns][1], bh1, acc[ns], 0, 0, 0);
                    acc[ns] = __builtin_amdgcn_mfma_f32_16x16x32_f16(ah[ns][0], bl0, acc[ns], 0, 0, 0);
                    acc[ns] = __builtin_amdgcn_mfma_f32_16x16x32_f16(ah[ns][1], bl1, acc[ns], 0, 0, 0);
                    acc[ns] = __builtin_amdgcn_mfma_f32_16x16x32_f16(al[ns][0], bh0, acc[ns], 0, 0, 0);
                    acc[ns] = __builtin_amdgcn_mfma_f32_16x16x32_f16(al[ns][1], bh1, acc[ns], 0, 0, 0);
                }
#pragma unroll
                for (int ns = 0; ns < 4; ++ns)
#pragma unroll
                    for (int j = 0; j < 4; ++j) {
                        float sc = acc[ns][j];
                        bool lt = sc < minv[ns][j];
                        minv[ns][j] = lt ? sc : minv[ns][j];
                        mini[ns][j] = lt ? kabs : mini[ns][j];
                    }
            }

            if (s < 15) {
                const int nbuf = (s + 1) & 1;
#pragma unroll
                for (int p = 0; p < 8; ++p) {
                    int kk = p * 16 + (tid >> 4);
                    float4 v = sreg[p];
                    _Float16 h, lo; f16x4 hv, lv;
                    fsplit(v.x, h, lo); hv[0] = h; lv[0] = lo;
                    fsplit(v.y, h, lo); hv[1] = h; lv[1] = lo;
                    fsplit(v.z, h, lo); hv[2] = h; lv[2] = lo;
                    fsplit(v.w, h, lo); hv[3] = h; lv[3] = lo;
                    *reinterpret_cast<f16x4*>(&cbh_lds[nbuf][kk][(tid & 15) * 4]) = hv;
                    *reinterpret_cast<f16x4*>(&cbl_lds[nbuf][kk][(tid & 15) * 4]) = lv;
                }
            }
        }

#pragma unroll
        for (int m = 1; m < 16; m <<= 1) {
#pragma unroll
            for (int ns = 0; ns < 4; ++ns)
#pragma unroll
                for (int j = 0; j < 4; ++j) {
                    float ov = __shfl_xor(minv[ns][j], m, 64);
                    int   oi = __shfl_xor(mini[ns][j], m, 64);
                    if (ov < minv[ns][j] || (ov == minv[ns][j] && oi < mini[ns][j])) {
                        minv[ns][j] = ov; mini[ns][j] = oi;
                    }
                }
        }
        if (l4 == 0) {
#pragma unroll
            for (int ns = 0; ns < 4; ++ns)
#pragma unroll
                for (int j = 0; j < 4; ++j) {
                    int row = rg * 64 + ns * 16 + l16 * 4 + j;
                    mv_lds[kh][row] = minv[ns][j];
                    mi_lds[kh][row] = mini[ns][j];
                }
        }
        __syncthreads();
        if (tid < 128) {
            float v0 = mv_lds[0][tid], v1 = mv_lds[1][tid];
            ks_lds[tid] = (v1 < v0) ? mi_lds[1][tid] : mi_lds[0][tid];
        }
        __syncthreads();

        {
            int n  = tid >> 1;
            int db = (tid & 1) * 32;
            int kw = ks_lds[n];
            const float* qp = &cbl_g[(size_t)kw * ND + db];
#pragma unroll
            for (int i = 0; i < 8; ++i) {
                float4 q  = *reinterpret_cast<const float4*>(&qp[i * 4]);
                float* rp = &r_lds[n][db + i * 4];
                float4 rv = *reinterpret_cast<float4*>(rp);
                rv.x -= q.x; rv.y -= q.y; rv.z -= q.z; rv.w -= q.w;
                *reinterpret_cast<float4*>(rp) = rv;
            }
        }
        __syncthreads();
    }

    float* ob = out + ((size_t)(b * NC + g * ND)) * NHW + n0;
#pragma unroll
    for (int dd = 0; dd < 8; ++dd) {
        int d = (tid >> 5) + dd * 8;
        int n = (tid & 31) * 4;
        float4 xv = *reinterpret_cast<const float4*>(&xb[(size_t)d * NHW + n]);
        float4 ov;
        ov.x = xv.x - r_lds[n + 0][d];
        ov.y = xv.y - r_lds[n + 1][d];
        ov.z = xv.z - r_lds[n + 2][d];
        ov.w = xv.w - r_lds[n + 3][d];
        *reinterpret_cast<float4*>(&ob[(size_t)d * NHW + n]) = ov;
    }
}

extern "C" void kernel_launch(void* const* d_in, const int* in_sizes, int n_in,
                              void* d_out, int out_size, void* d_ws, size_t ws_size,
                              hipStream_t stream) {
    const float* x  = (const float*)d_in[0];   // [B, C, H, W]
    const float* cb = (const float*)d_in[1];   // [L, G, K, D]
    float* out = (float*)d_out;

    const size_t FRAG_BYTES = (size_t)NL * NG * NK * ND * 2 * 2;  // 8 MiB
    const size_t NEED = FRAG_BYTES + (size_t)NL * NG * NK * 4;    // + cn

    if (ws_size >= NEED) {
        _Float16* wfrag = (_Float16*)d_ws;
        float* cn = (float*)((char*)d_ws + FRAG_BYTES);
        cq_prep32_kernel<<<256, 256, 0, stream>>>(cb, wfrag, cn);
        cq_main8_kernel<<<NB * NG * (NHW / 32), 256, 0, stream>>>(x, cb, wfrag, cn, out);
    } else {
        float* cn = (float*)d_ws;
        cq_cnorm_kernel<<<(NL * NG * NK) / 256, 256, 0, stream>>>(cb, cn);
        cq_main_kernel<<<NB * NG * (NHW / 128), 256, 0, stream>>>(x, cb, cn, out);
    }
}

// Round 9
// 124.760 us; speedup vs baseline: 5.2320x; 5.2320x over previous
//
#include <hip/hip_runtime.h>

#define NB 8
#define NC 256
#define NHW 1024   // H*W
#define NL 4
#define NG 4
#define NK 2048
#define ND 64      // C/G

#define RS 68      // r_lds row stride (floats)
#define CS 72      // (fallback kernel) codebook LDS row stride (halfs)

typedef __attribute__((ext_vector_type(8))) _Float16 f16x8;
typedef __attribute__((ext_vector_type(4))) _Float16 f16x4;
typedef __attribute__((ext_vector_type(4))) float    f32x4;

// fp16 hi/lo split: v = h + l + O(2^-24 v). Products h*h etc are exact in fp32.
__device__ __forceinline__ void fsplit(float v, _Float16& h, _Float16& l) {
    _Float16 hh = (_Float16)v;
    h = hh;
    l = (_Float16)(v - (float)hh);
}

// ---------------- fast path: prep kernel (16x16 fragment tiles) ----------------
// Per 16-codeword tile: 4 fragments (hiC0, hiC1, loC0, loC1), each 64 lanes x
// 8 halfs, lane-linear (one dwordx4 per lane in the main kernel). Fused cn.
__global__ void cq_prep_kernel(const float* __restrict__ cb,
                               _Float16* __restrict__ wfrag,
                               float* __restrict__ cn) {
    int wv   = (blockIdx.x * 256 + threadIdx.x) >> 6;  // tile id 0..2047
    int lane = threadIdx.x & 63;
    int l4 = lane & 15, l16 = lane >> 4;
    int lg = wv >> 7, kt = wv & 127;
    int k  = kt * 16 + l4;
    const float* src = cb + ((size_t)lg * NK + k) * ND;

    float4 a0 = *(const float4*)(src + l16 * 8);
    float4 a1 = *(const float4*)(src + l16 * 8 + 4);
    float4 b0 = *(const float4*)(src + 32 + l16 * 8);
    float4 b1 = *(const float4*)(src + 32 + l16 * 8 + 4);

    f16x8 h0, lo0, h1, lo1;
    _Float16 h, lo;
    fsplit(a0.x,h,lo); h0[0]=h; lo0[0]=lo;  fsplit(a0.y,h,lo); h0[1]=h; lo0[1]=lo;
    fsplit(a0.z,h,lo); h0[2]=h; lo0[2]=lo;  fsplit(a0.w,h,lo); h0[3]=h; lo0[3]=lo;
    fsplit(a1.x,h,lo); h0[4]=h; lo0[4]=lo;  fsplit(a1.y,h,lo); h0[5]=h; lo0[5]=lo;
    fsplit(a1.z,h,lo); h0[6]=h; lo0[6]=lo;  fsplit(a1.w,h,lo); h0[7]=h; lo0[7]=lo;
    fsplit(b0.x,h,lo); h1[0]=h; lo1[0]=lo;  fsplit(b0.y,h,lo); h1[1]=h; lo1[1]=lo;
    fsplit(b0.z,h,lo); h1[2]=h; lo1[2]=lo;  fsplit(b0.w,h,lo); h1[3]=h; lo1[3]=lo;
    fsplit(b1.x,h,lo); h1[4]=h; lo1[4]=lo;  fsplit(b1.y,h,lo); h1[5]=h; lo1[5]=lo;
    fsplit(b1.z,h,lo); h1[6]=h; lo1[6]=lo;  fsplit(b1.w,h,lo); h1[7]=h; lo1[7]=lo;

    _Float16* outp = wfrag + (size_t)wv * 2048;   // tile = 4096 B
    *(f16x8*)(outp +    0 + lane * 8) = h0;
    *(f16x8*)(outp +  512 + lane * 8) = h1;
    *(f16x8*)(outp + 1024 + lane * 8) = lo0;
    *(f16x8*)(outp + 1536 + lane * 8) = lo1;

    float s = a0.x*a0.x + a0.y*a0.y + a0.z*a0.z + a0.w*a0.w
            + a1.x*a1.x + a1.y*a1.y + a1.z*a1.z + a1.w*a1.w
            + b0.x*b0.x + b0.y*b0.y + b0.z*b0.z + b0.w*b0.w
            + b1.x*b1.x + b1.y*b1.y + b1.z*b1.z + b1.w*b1.w;
    s += __shfl_xor(s, 16, 64);
    s += __shfl_xor(s, 32, 64);
    if (l16 == 0) cn[(size_t)lg * NK + k] = 0.5f * s;
}

// ---------------- fast path: main kernel v9 ----------------
// v7 geometry (1024 blocks x 256 threads, 32 rows/block, wave = k-quarter)
// with: X/Y register dbuf + sched_barrier(0) anti-sink fences (replaces the
// copy idiom's 16 movs/stage), rolling-pointer addressing (imm offsets
// 0/1024/2048/3072B), setprio around the MFMA cluster, cap 128 VGPR.
__global__ __launch_bounds__(256, 4) void cq_main9_kernel(
    const float* __restrict__ x, const float* __restrict__ cb,
    const _Float16* __restrict__ wfrag, const float* __restrict__ cn,
    float* __restrict__ out)
{
    __shared__ float r_lds[32][RS];
    __shared__ float mv_lds[4][32];
    __shared__ int   mi_lds[4][32];
    __shared__ int   ks_lds[32];

    const int tid = threadIdx.x;
    // bijective XCD swizzle (1024 = 8 XCD * 128)
    const int blk = (blockIdx.x & 7) * 128 + (blockIdx.x >> 3);
    const int nt  = blk & 31;
    const int g   = (blk >> 5) & 3;
    const int b   = blk >> 7;
    const int n0  = nt * 32;

    const float* xb = x + ((size_t)(b * NC + g * ND)) * NHW + n0;
#pragma unroll
    for (int dd = 0; dd < 2; ++dd) {
        int d = (tid >> 3) + dd * 32;
        int n = (tid & 7) * 4;
        float4 xv = *(const float4*)(&xb[(size_t)d * NHW + n]);
        r_lds[n + 0][d] = xv.x; r_lds[n + 1][d] = xv.y;
        r_lds[n + 2][d] = xv.z; r_lds[n + 3][d] = xv.w;
    }
    __syncthreads();

    const int lane = tid & 63;
    const int kq   = tid >> 6;        // k-quarter (4 waves)
    const int l4   = lane & 15;
    const int l16  = lane >> 4;
    const int kbase = kq * 512;

    for (int l = 0; l < NL; ++l) {
        const float* cbl_g = cb + (size_t)(l * NG + g) * NK * ND;
        const float* cnl   = cn + (size_t)(l * NG + g) * NK;

        // negated hi/lo A fragments: rows ns*16+l4, d = c*32+l16*8+j
        f16x8 ah[2][2], al[2][2];
#pragma unroll
        for (int ns = 0; ns < 2; ++ns) {
#pragma unroll
            for (int c = 0; c < 2; ++c) {
                const float* rp = &r_lds[ns * 16 + l4][c * 32 + l16 * 8];
                float4 v0 = *(const float4*)(rp);
                float4 v1 = *(const float4*)(rp + 4);
                _Float16 h, lo; f16x8 hv, lv;
                fsplit(-v0.x,h,lo); hv[0]=h; lv[0]=lo;
                fsplit(-v0.y,h,lo); hv[1]=h; lv[1]=lo;
                fsplit(-v0.z,h,lo); hv[2]=h; lv[2]=lo;
                fsplit(-v0.w,h,lo); hv[3]=h; lv[3]=lo;
                fsplit(-v1.x,h,lo); hv[4]=h; lv[4]=lo;
                fsplit(-v1.y,h,lo); hv[5]=h; lv[5]=lo;
                fsplit(-v1.z,h,lo); hv[6]=h; lv[6]=lo;
                fsplit(-v1.w,h,lo); hv[7]=h; lv[7]=lo;
                ah[ns][c] = hv; al[ns][c] = lv;
            }
        }

        float minv[2][4];
        int   mini[2][4];
#pragma unroll
        for (int i = 0; i < 2; ++i)
#pragma unroll
            for (int j = 0; j < 4; ++j) { minv[i][j] = 3.4e38f; mini[i][j] = 0; }

        // rolling pointers: fragment base (stage stride 2048 halfs = 4096 B)
        // and cn pointer (stride 16 floats). Loads use imm offsets.
        const _Float16* ph = wfrag + ((size_t)(l * NG + g) * 128 + kq * 32) * 2048
                           + lane * 8;
        const float*    pc = cnl + kbase + l4;
        int kcur = kbase + l4;

        f16x8 Xh[2], Xl[2], Yh[2], Yl[2];
        float cvX, cvY;

        auto LD = [&](f16x8 (&H)[2], f16x8 (&L)[2], float& cv) {
            H[0] = *(const f16x8*)(ph);
            H[1] = *(const f16x8*)(ph + 512);
            L[0] = *(const f16x8*)(ph + 1024);
            L[1] = *(const f16x8*)(ph + 1536);
            cv = *pc;
            ph += 2048; pc += 16;
        };

        // exact v7 MFMA order + cv-in-init -> numerics identical to v7
        auto ST = [&](const f16x8 (&H)[2], const f16x8 (&L)[2], float cv) {
            f32x4 a0 = {cv, cv, cv, cv};
            f32x4 a1 = {cv, cv, cv, cv};
            __builtin_amdgcn_s_setprio(1);
            a0 = __builtin_amdgcn_mfma_f32_16x16x32_f16(ah[0][0], H[0], a0, 0, 0, 0);
            a0 = __builtin_amdgcn_mfma_f32_16x16x32_f16(ah[0][1], H[1], a0, 0, 0, 0);
            a0 = __builtin_amdgcn_mfma_f32_16x16x32_f16(ah[0][0], L[0], a0, 0, 0, 0);
            a0 = __builtin_amdgcn_mfma_f32_16x16x32_f16(ah[0][1], L[1], a0, 0, 0, 0);
            a0 = __builtin_amdgcn_mfma_f32_16x16x32_f16(al[0][0], H[0], a0, 0, 0, 0);
            a0 = __builtin_amdgcn_mfma_f32_16x16x32_f16(al[0][1], H[1], a0, 0, 0, 0);
            a1 = __builtin_amdgcn_mfma_f32_16x16x32_f16(ah[1][0], H[0], a1, 0, 0, 0);
            a1 = __builtin_amdgcn_mfma_f32_16x16x32_f16(ah[1][1], H[1], a1, 0, 0, 0);
            a1 = __builtin_amdgcn_mfma_f32_16x16x32_f16(ah[1][0], L[0], a1, 0, 0, 0);
            a1 = __builtin_amdgcn_mfma_f32_16x16x32_f16(ah[1][1], L[1], a1, 0, 0, 0);
            a1 = __builtin_amdgcn_mfma_f32_16x16x32_f16(al[1][0], H[0], a1, 0, 0, 0);
            a1 = __builtin_amdgcn_mfma_f32_16x16x32_f16(al[1][1], H[1], a1, 0, 0, 0);
            __builtin_amdgcn_s_setprio(0);
#pragma unroll
            for (int j = 0; j < 4; ++j) {
                bool lt0 = a0[j] < minv[0][j];
                minv[0][j] = lt0 ? a0[j] : minv[0][j];
                mini[0][j] = lt0 ? kcur : mini[0][j];
                bool lt1 = a1[j] < minv[1][j];
                minv[1][j] = lt1 ? a1[j] : minv[1][j];
                mini[1][j] = lt1 ? kcur : mini[1][j];
            }
            kcur += 16;
        };

        LD(Xh, Xl, cvX);                    // stage 0
#pragma unroll 2
        for (int i = 0; i < 16; ++i) {
            LD(Yh, Yl, cvY);                // stage 2i+1
            __builtin_amdgcn_sched_barrier(0);
            ST(Xh, Xl, cvX);                // stage 2i
            if (i < 15) LD(Xh, Xl, cvX);    // stage 2i+2
            __builtin_amdgcn_sched_barrier(0);
            ST(Yh, Yl, cvY);                // stage 2i+1
        }

        // reduce over the 16 k-lanes (ties -> lower k)
#pragma unroll
        for (int m = 1; m < 16; m <<= 1) {
#pragma unroll
            for (int ns = 0; ns < 2; ++ns)
#pragma unroll
                for (int j = 0; j < 4; ++j) {
                    float ov = __shfl_xor(minv[ns][j], m, 64);
                    int   oi = __shfl_xor(mini[ns][j], m, 64);
                    if (ov < minv[ns][j] || (ov == minv[ns][j] && oi < mini[ns][j])) {
                        minv[ns][j] = ov; mini[ns][j] = oi;
                    }
                }
        }
        if (l4 == 0) {
#pragma unroll
            for (int ns = 0; ns < 2; ++ns)
#pragma unroll
                for (int j = 0; j < 4; ++j) {
                    int row = ns * 16 + l16 * 4 + j;   // C/D: row=(lane>>4)*4+reg
                    mv_lds[kq][row] = minv[ns][j];
                    mi_lds[kq][row] = mini[ns][j];
                }
        }
        __syncthreads();
        if (tid < 32) {   // combine 4 quarters ascending (tie -> lower k)
            float bv = mv_lds[0][tid]; int bi = mi_lds[0][tid];
#pragma unroll
            for (int q = 1; q < 4; ++q) {
                float v = mv_lds[q][tid];
                if (v < bv) { bv = v; bi = mi_lds[q][tid]; }
            }
            ks_lds[tid] = bi;
        }
        __syncthreads();

        // r -= cb[k*]  (exact fp32, rows L2-hot)
        {
            int row = tid >> 3, dc = (tid & 7) * 8;
            int kw = ks_lds[row];
            const float* qp = cbl_g + (size_t)kw * ND + dc;
#pragma unroll
            for (int i = 0; i < 2; ++i) {
                float4 q  = *(const float4*)(qp + i * 4);
                float* rp = &r_lds[row][dc + i * 4];
                float4 rv = *(float4*)rp;
                rv.x -= q.x; rv.y -= q.y; rv.z -= q.z; rv.w -= q.w;
                *(float4*)rp = rv;
            }
        }
        __syncthreads();
    }

    // out = x - r_final
    float* ob = out + ((size_t)(b * NC + g * ND)) * NHW + n0;
#pragma unroll
    for (int dd = 0; dd < 2; ++dd) {
        int d = (tid >> 3) + dd * 32;
        int n = (tid & 7) * 4;
        float4 xv = *(const float4*)(&xb[(size_t)d * NHW + n]);
        float4 ov;
        ov.x = xv.x - r_lds[n + 0][d];
        ov.y = xv.y - r_lds[n + 1][d];
        ov.z = xv.z - r_lds[n + 2][d];
        ov.w = xv.w - r_lds[n + 3][d];
        *(float4*)(&ob[(size_t)d * NHW + n]) = ov;
    }
}

// ---------------- fallback path (round-2 kernels, 128 KB ws) ----------------
__global__ void cq_cnorm_kernel(const float* __restrict__ cb, float* __restrict__ cn) {
    int idx = blockIdx.x * 256 + threadIdx.x;
    const float4* p = reinterpret_cast<const float4*>(cb + (size_t)idx * ND);
    float s = 0.f;
#pragma unroll
    for (int i = 0; i < ND / 4; ++i) {
        float4 v = p[i];
        s += v.x * v.x + v.y * v.y + v.z * v.z + v.w * v.w;
    }
    cn[idx] = 0.5f * s;
}

__global__ __launch_bounds__(256, 1) void cq_main_kernel(
    const float* __restrict__ x, const float* __restrict__ cb,
    const float* __restrict__ cn, float* __restrict__ out)
{
    __shared__ float    r_lds[128][RS];
    __shared__ _Float16 cbh_lds[2][128][CS];
    __shared__ _Float16 cbl_lds[2][128][CS];
    __shared__ float    mv_lds[2][128];
    __shared__ int      mi_lds[2][128];
    __shared__ int      ks_lds[128];

    const int tid = threadIdx.x;
    const int blk = blockIdx.x;
    const int nt  = blk & 7;
    const int bg  = blk >> 3;
    const int g   = bg & 3;
    const int b   = bg >> 2;
    const int n0  = nt * 128;

    const float* xb = x + ((size_t)(b * NC + g * ND)) * NHW + n0;
#pragma unroll
    for (int dd = 0; dd < 8; ++dd) {
        int d = (tid >> 5) + dd * 8;
        int n = (tid & 31) * 4;
        float4 xv = *reinterpret_cast<const float4*>(&xb[(size_t)d * NHW + n]);
        r_lds[n + 0][d] = xv.x; r_lds[n + 1][d] = xv.y;
        r_lds[n + 2][d] = xv.z; r_lds[n + 3][d] = xv.w;
    }

    const int lane = tid & 63;
    const int wid  = tid >> 6;
    const int rg   = wid & 1;
    const int kh   = wid >> 1;
    const int l4   = lane & 15;
    const int l16  = lane >> 4;

    __syncthreads();

    for (int l = 0; l < NL; ++l) {
        const float* cbl_g = cb + (size_t)(l * NG + g) * NK * ND;
        const float* cnl   = cn + (size_t)(l * NG + g) * NK;

        f16x8 ah[4][2], al[4][2];
#pragma unroll
        for (int ns = 0; ns < 4; ++ns) {
#pragma unroll
            for (int c = 0; c < 2; ++c) {
                const float* rp = &r_lds[rg * 64 + ns * 16 + l4][c * 32 + l16 * 8];
                float4 v0 = *reinterpret_cast<const float4*>(rp);
                float4 v1 = *reinterpret_cast<const float4*>(rp + 4);
                _Float16 h, lo; f16x8 hv, lv;
                fsplit(-v0.x, h, lo); hv[0] = h; lv[0] = lo;
                fsplit(-v0.y, h, lo); hv[1] = h; lv[1] = lo;
                fsplit(-v0.z, h, lo); hv[2] = h; lv[2] = lo;
                fsplit(-v0.w, h, lo); hv[3] = h; lv[3] = lo;
                fsplit(-v1.x, h, lo); hv[4] = h; lv[4] = lo;
                fsplit(-v1.y, h, lo); hv[5] = h; lv[5] = lo;
                fsplit(-v1.z, h, lo); hv[6] = h; lv[6] = lo;
                fsplit(-v1.w, h, lo); hv[7] = h; lv[7] = lo;
                ah[ns][c] = hv; al[ns][c] = lv;
            }
        }

        float minv[4][4];
        int   mini[4][4];
#pragma unroll
        for (int i = 0; i < 4; ++i)
#pragma unroll
            for (int j = 0; j < 4; ++j) { minv[i][j] = 3.4e38f; mini[i][j] = 0; }

        float4 sreg[8];
#pragma unroll
        for (int p = 0; p < 8; ++p) {
            int kk = p * 16 + (tid >> 4);
            int kg = (kk < 64) ? kk : (1024 - 64 + kk);
            sreg[p] = *reinterpret_cast<const float4*>(&cbl_g[(size_t)kg * ND + (tid & 15) * 4]);
        }
#pragma unroll
        for (int p = 0; p < 8; ++p) {
            int kk = p * 16 + (tid >> 4);
            float4 v = sreg[p];
            _Float16 h, lo; f16x4 hv, lv;
            fsplit(v.x, h, lo); hv[0] = h; lv[0] = lo;
            fsplit(v.y, h, lo); hv[1] = h; lv[1] = lo;
            fsplit(v.z, h, lo); hv[2] = h; lv[2] = lo;
            fsplit(v.w, h, lo); hv[3] = h; lv[3] = lo;
            *reinterpret_cast<f16x4*>(&cbh_lds[0][kk][(tid & 15) * 4]) = hv;
            *reinterpret_cast<f16x4*>(&cbl_lds[0][kk][(tid & 15) * 4]) = lv;
        }

        for (int s = 0; s < 16; ++s) {
            __syncthreads();

            if (s < 15) {
#pragma unroll
                for (int p = 0; p < 8; ++p) {
                    int kk = p * 16 + (tid >> 4);
                    int kg = (kk < 64) ? ((s + 1) * 64 + kk) : (1024 + (s + 1) * 64 + (kk - 64));
                    sreg[p] = *reinterpret_cast<const float4*>(&cbl_g[(size_t)kg * ND + (tid & 15) * 4]);
                }
            }

            const int buf = s & 1;
            for (int ks = 0; ks < 4; ++ks) {
                int lrow = kh * 64 + ks * 16 + l4;
                int kabs = kh * 1024 + s * 64 + ks * 16 + l4;
                f16x8 bh0 = *reinterpret_cast<const f16x8*>(&cbh_lds[buf][lrow][l16 * 8]);
                f16x8 bh1 = *reinterpret_cast<const f16x8*>(&cbh_lds[buf][lrow][32 + l16 * 8]);
                f16x8 bl0 = *reinterpret_cast<const f16x8*>(&cbl_lds[buf][lrow][l16 * 8]);
                f16x8 bl1 = *reinterpret_cast<const f16x8*>(&cbl_lds[buf][lrow][32 + l16 * 8]);
                float cnv = cnl[kabs];
                f32x4 acc[4];
#pragma unroll
                for (int ns = 0; ns < 4; ++ns) acc[ns] = (f32x4){cnv, cnv, cnv, cnv};
#pragma unroll
                for (int ns = 0; ns < 4; ++ns) {
                    acc[ns] = __builtin_amdgcn_mfma_f32_16x16x32_f16(ah[ns][0], bh0, acc[ns], 0, 0, 0);
                    acc[ns] = __builtin_amdgcn_mfma_f32_16x16x32_f16(ah[ns][1], bh1, acc[ns], 0, 0, 0);
                    acc[ns] = __builtin_amdgcn_mfma_f32_16x16x32_f16(ah[ns][0], bl0, acc[ns], 0, 0, 0);
                    acc[ns] = __builtin_amdgcn_mfma_f32_16x16x32_f16(ah[ns][1], bl1, acc[ns], 0, 0, 0);
                    acc[ns] = __builtin_amdgcn_mfma_f32_16x16x32_f16(al[ns][0], bh0, acc[ns], 0, 0, 0);
                    acc[ns] = __builtin_amdgcn_mfma_f32_16x16x32_f16(al[ns][1], bh1, acc[ns], 0, 0, 0);
                }
#pragma unroll
                for (int ns = 0; ns < 4; ++ns)
#pragma unroll
                    for (int j = 0; j < 4; ++j) {
                        float sc = acc[ns][j];
                        bool lt = sc < minv[ns][j];
                        minv[ns][j] = lt ? sc : minv[ns][j];
                        mini[ns][j] = lt ? kabs : mini[ns][j];
                    }
            }

            if (s < 15) {
                const int nbuf = (s + 1) & 1;
#pragma unroll
                for (int p = 0; p < 8; ++p) {
                    int kk = p * 16 + (tid >> 4);
                    float4 v = sreg[p];
                    _Float16 h, lo; f16x4 hv, lv;
                    fsplit(v.x, h, lo); hv[0] = h; lv[0] = lo;
                    fsplit(v.y, h, lo); hv[1] = h; lv[1] = lo;
                    fsplit(v.z, h, lo); hv[2] = h; lv[2] = lo;
                    fsplit(v.w, h, lo); hv[3] = h; lv[3] = lo;
                    *reinterpret_cast<f16x4*>(&cbh_lds[nbuf][kk][(tid & 15) * 4]) = hv;
                    *reinterpret_cast<f16x4*>(&cbl_lds[nbuf][kk][(tid & 15) * 4]) = lv;
                }
            }
        }

#pragma unroll
        for (int m = 1; m < 16; m <<= 1) {
#pragma unroll
            for (int ns = 0; ns < 4; ++ns)
#pragma unroll
                for (int j = 0; j < 4; ++j) {
                    float ov = __shfl_xor(minv[ns][j], m, 64);
                    int   oi = __shfl_xor(mini[ns][j], m, 64);
                    if (ov < minv[ns][j] || (ov == minv[ns][j] && oi < mini[ns][j])) {
                        minv[ns][j] = ov; mini[ns][j] = oi;
                    }
                }
        }
        if (l4 == 0) {
#pragma unroll
            for (int ns = 0; ns < 4; ++ns)
#pragma unroll
                for (int j = 0; j < 4; ++j) {
                    int row = rg * 64 + ns * 16 + l16 * 4 + j;
                    mv_lds[kh][row] = minv[ns][j];
                    mi_lds[kh][row] = mini[ns][j];
                }
        }
        __syncthreads();
        if (tid < 128) {
            float v0 = mv_lds[0][tid], v1 = mv_lds[1][tid];
            ks_lds[tid] = (v1 < v0) ? mi_lds[1][tid] : mi_lds[0][tid];
        }
        __syncthreads();

        {
            int n  = tid >> 1;
            int db = (tid & 1) * 32;
            int kw = ks_lds[n];
            const float* qp = &cbl_g[(size_t)kw * ND + db];
#pragma unroll
            for (int i = 0; i < 8; ++i) {
                float4 q  = *reinterpret_cast<const float4*>(&qp[i * 4]);
                float* rp = &r_lds[n][db + i * 4];
                float4 rv = *reinterpret_cast<float4*>(rp);
                rv.x -= q.x; rv.y -= q.y; rv.z -= q.z; rv.w -= q.w;
                *reinterpret_cast<float4*>(rp) = rv;
            }
        }
        __syncthreads();
    }

    float* ob = out + ((size_t)(b * NC + g * ND)) * NHW + n0;
#pragma unroll
    for (int dd = 0; dd < 8; ++dd) {
        int d = (tid >> 5) + dd * 8;
        int n = (tid & 31) * 4;
        float4 xv = *reinterpret_cast<const float4*>(&xb[(size_t)d * NHW + n]);
        float4 ov;
        ov.x = xv.x - r_lds[n + 0][d];
        ov.y = xv.y - r_lds[n + 1][d];
        ov.z = xv.z - r_lds[n + 2][d];
        ov.w = xv.w - r_lds[n + 3][d];
        *reinterpret_cast<float4*>(&ob[(size_t)d * NHW + n]) = ov;
    }
}

extern "C" void kernel_launch(void* const* d_in, const int* in_sizes, int n_in,
                              void* d_out, int out_size, void* d_ws, size_t ws_size,
                              hipStream_t stream) {
    const float* x  = (const float*)d_in[0];   // [B, C, H, W]
    const float* cb = (const float*)d_in[1];   // [L, G, K, D]
    float* out = (float*)d_out;

    const size_t FRAG_BYTES = (size_t)NL * NG * NK * ND * 2 * 2;  // 8 MiB
    const size_t NEED = FRAG_BYTES + (size_t)NL * NG * NK * 4;    // + cn

    if (ws_size >= NEED) {
        _Float16* wfrag = (_Float16*)d_ws;
        float* cn = (float*)((char*)d_ws + FRAG_BYTES);
        cq_prep_kernel<<<512, 256, 0, stream>>>(cb, wfrag, cn);
        cq_main9_kernel<<<NB * NG * (NHW / 32), 256, 0, stream>>>(x, cb, wfrag, cn, out);
    } else {
        float* cn = (float*)d_ws;
        cq_cnorm_kernel<<<(NL * NG * NK) / 256, 256, 0, stream>>>(cb, cn);
        cq_main_kernel<<<NB * NG * (NHW / 128), 256, 0, stream>>>(x, cb, cn, out);
    }
}

// Round 11
// 120.813 us; speedup vs baseline: 5.4030x; 1.0327x over previous
//
#include <hip/hip_runtime.h>

#define NB 8
#define NC 256
#define NHW 1024   // H*W
#define NL 4
#define NG 4
#define NK 2048
#define ND 64      // C/G

#define RS 68      // r_lds row stride (floats)
#define CS 72      // (fallback kernel) codebook LDS row stride (halfs)

typedef __attribute__((ext_vector_type(8))) _Float16 f16x8;
typedef __attribute__((ext_vector_type(4))) _Float16 f16x4;
typedef __attribute__((ext_vector_type(4))) float    f32x4;

// fp16 hi/lo split: v = h + l + O(2^-24 v). Products h*h etc are exact in fp32.
__device__ __forceinline__ void fsplit(float v, _Float16& h, _Float16& l) {
    _Float16 hh = (_Float16)v;
    h = hh;
    l = (_Float16)(v - (float)hh);
}

// ---------------- fast path: prep kernel ----------------
// Per 16-codeword tile: 4 fragments (hiC0, hiC1, loC0, loC1), each 64 lanes x
// 8 halfs, lane-linear (one dwordx4 per lane in the main kernel). Fused cn.
__global__ void cq_prep_kernel(const float* __restrict__ cb,
                               _Float16* __restrict__ wfrag,
                               float* __restrict__ cn) {
    int wv   = (blockIdx.x * 256 + threadIdx.x) >> 6;  // tile id 0..2047
    int lane = threadIdx.x & 63;
    int l4 = lane & 15, l16 = lane >> 4;
    int lg = wv >> 7, kt = wv & 127;
    int k  = kt * 16 + l4;
    const float* src = cb + ((size_t)lg * NK + k) * ND;

    float4 a0 = *(const float4*)(src + l16 * 8);
    float4 a1 = *(const float4*)(src + l16 * 8 + 4);
    float4 b0 = *(const float4*)(src + 32 + l16 * 8);
    float4 b1 = *(const float4*)(src + 32 + l16 * 8 + 4);

    f16x8 h0, lo0, h1, lo1;
    _Float16 h, lo;
    fsplit(a0.x,h,lo); h0[0]=h; lo0[0]=lo;  fsplit(a0.y,h,lo); h0[1]=h; lo0[1]=lo;
    fsplit(a0.z,h,lo); h0[2]=h; lo0[2]=lo;  fsplit(a0.w,h,lo); h0[3]=h; lo0[3]=lo;
    fsplit(a1.x,h,lo); h0[4]=h; lo0[4]=lo;  fsplit(a1.y,h,lo); h0[5]=h; lo0[5]=lo;
    fsplit(a1.z,h,lo); h0[6]=h; lo0[6]=lo;  fsplit(a1.w,h,lo); h0[7]=h; lo0[7]=lo;
    fsplit(b0.x,h,lo); h1[0]=h; lo1[0]=lo;  fsplit(b0.y,h,lo); h1[1]=h; lo1[1]=lo;
    fsplit(b0.z,h,lo); h1[2]=h; lo1[2]=lo;  fsplit(b0.w,h,lo); h1[3]=h; lo1[3]=lo;
    fsplit(b1.x,h,lo); h1[4]=h; lo1[4]=lo;  fsplit(b1.y,h,lo); h1[5]=h; lo1[5]=lo;
    fsplit(b1.z,h,lo); h1[6]=h; lo1[6]=lo;  fsplit(b1.w,h,lo); h1[7]=h; lo1[7]=lo;

    _Float16* outp = wfrag + (size_t)wv * 2048;   // tile = 4096 B
    *(f16x8*)(outp +    0 + lane * 8) = h0;
    *(f16x8*)(outp +  512 + lane * 8) = h1;
    *(f16x8*)(outp + 1024 + lane * 8) = lo0;
    *(f16x8*)(outp + 1536 + lane * 8) = lo1;

    float s = a0.x*a0.x + a0.y*a0.y + a0.z*a0.z + a0.w*a0.w
            + a1.x*a1.x + a1.y*a1.y + a1.z*a1.z + a1.w*a1.w
            + b0.x*b0.x + b0.y*b0.y + b0.z*b0.z + b0.w*b0.w
            + b1.x*b1.x + b1.y*b1.y + b1.z*b1.z + b1.w*b1.w;
    s += __shfl_xor(s, 16, 64);
    s += __shfl_xor(s, 32, 64);
    if (l16 == 0) cn[(size_t)lg * NK + k] = 0.5f * s;
}

// ---------------- fast path: main kernel v11 ----------------
// v3's exact proven structure (512 blocks x 256 threads, 64 rows/block,
// wave = k-quarter, ns=4, copy-idiom pipeline) with pipeline depth 1 -> 2:
// three fragment sets {p: consuming, m: arrived, c: in flight}. Grid limits
// occupancy to 2 waves/SIMD regardless, so the extra ~50 VGPRs are free.
__global__ __launch_bounds__(256, 2) void cq_main11_kernel(
    const float* __restrict__ x, const float* __restrict__ cb,
    const _Float16* __restrict__ wfrag, const float* __restrict__ cn,
    float* __restrict__ out)
{
    __shared__ float r_lds[64][RS];
    __shared__ float mv_lds[4][64];
    __shared__ int   mi_lds[4][64];
    __shared__ int   ks_lds[64];

    const int tid = threadIdx.x;
    const int blk = blockIdx.x;       // 512 = 8b * 4g * 16nt
    const int nt  = blk & 15;
    const int g   = (blk >> 4) & 3;
    const int b   = blk >> 6;
    const int n0  = nt * 64;

    const float* xb = x + ((size_t)(b * NC + g * ND)) * NHW + n0;
#pragma unroll
    for (int dd = 0; dd < 4; ++dd) {
        int d = (tid >> 4) + dd * 16;
        int n = (tid & 15) * 4;
        float4 xv = *(const float4*)(&xb[(size_t)d * NHW + n]);
        r_lds[n + 0][d] = xv.x; r_lds[n + 1][d] = xv.y;
        r_lds[n + 2][d] = xv.z; r_lds[n + 3][d] = xv.w;
    }
    __syncthreads();

    const int lane = tid & 63;
    const int kq   = tid >> 6;        // k-quarter (4 waves)
    const int l4   = lane & 15;
    const int l16  = lane >> 4;
    const int kbase = kq * 512;

    for (int l = 0; l < NL; ++l) {
        const float* cbl_g = cb + (size_t)(l * NG + g) * NK * ND;
        const float* cnl   = cn + (size_t)(l * NG + g) * NK;
        const _Float16* fb = wfrag + ((size_t)(l * NG + g) * 128 + kq * 32) * 2048;

        // negated hi/lo A fragments: rows ns*16+l4, d = c*32+l16*8+j
        f16x8 ah[4][2], al[4][2];
#pragma unroll
        for (int ns = 0; ns < 4; ++ns) {
#pragma unroll
            for (int c = 0; c < 2; ++c) {
                const float* rp = &r_lds[ns * 16 + l4][c * 32 + l16 * 8];
                float4 v0 = *(const float4*)(rp);
                float4 v1 = *(const float4*)(rp + 4);
                _Float16 h, lo; f16x8 hv, lv;
                fsplit(-v0.x,h,lo); hv[0]=h; lv[0]=lo;
                fsplit(-v0.y,h,lo); hv[1]=h; lv[1]=lo;
                fsplit(-v0.z,h,lo); hv[2]=h; lv[2]=lo;
                fsplit(-v0.w,h,lo); hv[3]=h; lv[3]=lo;
                fsplit(-v1.x,h,lo); hv[4]=h; lv[4]=lo;
                fsplit(-v1.y,h,lo); hv[5]=h; lv[5]=lo;
                fsplit(-v1.z,h,lo); hv[6]=h; lv[6]=lo;
                fsplit(-v1.w,h,lo); hv[7]=h; lv[7]=lo;
                ah[ns][c] = hv; al[ns][c] = lv;
            }
        }

        float minv[4][4];
        int   mini[4][4];
#pragma unroll
        for (int i = 0; i < 4; ++i)
#pragma unroll
            for (int j = 0; j < 4; ++j) { minv[i][j] = 3.4e38f; mini[i][j] = 0; }

        // 2-deep pipeline: stage 0 -> m (arrived-next), stage 1 -> c (in flight)
        f16x8 m0, m1, m2, m3, c0, c1, c2, c3;
        float cvm, cvc;
        {
            const _Float16* p = fb + lane * 8;
            m0 = *(const f16x8*)(p);
            m1 = *(const f16x8*)(p + 512);
            m2 = *(const f16x8*)(p + 1024);
            m3 = *(const f16x8*)(p + 1536);
            cvm = cnl[kbase + l4];
        }
        {
            const _Float16* p = fb + 2048 + lane * 8;
            c0 = *(const f16x8*)(p);
            c1 = *(const f16x8*)(p + 512);
            c2 = *(const f16x8*)(p + 1024);
            c3 = *(const f16x8*)(p + 1536);
            cvc = cnl[kbase + 16 + l4];
        }

#pragma unroll 2
        for (int s = 0; s < 32; ++s) {
            // rotate: p <- m <- c   (copies force load-early/use-late ordering)
            f16x8 p0 = m0, p1 = m1, p2 = m2, p3 = m3; float pv = cvm;
            m0 = c0; m1 = c1; m2 = c2; m3 = c3; cvm = cvc;
            if (s < 30) {   // issue stage s+2 (2 stage-walls of latency cover)
                const _Float16* p = fb + (size_t)(s + 2) * 2048 + lane * 8;
                c0 = *(const f16x8*)(p);
                c1 = *(const f16x8*)(p + 512);
                c2 = *(const f16x8*)(p + 1024);
                c3 = *(const f16x8*)(p + 1536);
                cvc = cnl[kbase + (s + 2) * 16 + l4];
            }
            const int kabs = kbase + s * 16 + l4;
            f32x4 acc[4];
#pragma unroll
            for (int ns = 0; ns < 4; ++ns) acc[ns] = (f32x4){pv, pv, pv, pv};
#pragma unroll
            for (int ns = 0; ns < 4; ++ns) {
                acc[ns] = __builtin_amdgcn_mfma_f32_16x16x32_f16(ah[ns][0], p0, acc[ns], 0, 0, 0);
                acc[ns] = __builtin_amdgcn_mfma_f32_16x16x32_f16(ah[ns][1], p1, acc[ns], 0, 0, 0);
                acc[ns] = __builtin_amdgcn_mfma_f32_16x16x32_f16(ah[ns][0], p2, acc[ns], 0, 0, 0);
                acc[ns] = __builtin_amdgcn_mfma_f32_16x16x32_f16(ah[ns][1], p3, acc[ns], 0, 0, 0);
                acc[ns] = __builtin_amdgcn_mfma_f32_16x16x32_f16(al[ns][0], p0, acc[ns], 0, 0, 0);
                acc[ns] = __builtin_amdgcn_mfma_f32_16x16x32_f16(al[ns][1], p1, acc[ns], 0, 0, 0);
            }
#pragma unroll
            for (int ns = 0; ns < 4; ++ns)
#pragma unroll
                for (int j = 0; j < 4; ++j) {
                    float sc = acc[ns][j];
                    bool lt = sc < minv[ns][j];
                    minv[ns][j] = lt ? sc : minv[ns][j];
                    mini[ns][j] = lt ? kabs : mini[ns][j];
                }
        }

        // reduce over the 16 k-lanes (ties -> lower k)
#pragma unroll
        for (int m = 1; m < 16; m <<= 1) {
#pragma unroll
            for (int ns = 0; ns < 4; ++ns)
#pragma unroll
                for (int j = 0; j < 4; ++j) {
                    float ov = __shfl_xor(minv[ns][j], m, 64);
                    int   oi = __shfl_xor(mini[ns][j], m, 64);
                    if (ov < minv[ns][j] || (ov == minv[ns][j] && oi < mini[ns][j])) {
                        minv[ns][j] = ov; mini[ns][j] = oi;
                    }
                }
        }
        if (l4 == 0) {
#pragma unroll
            for (int ns = 0; ns < 4; ++ns)
#pragma unroll
                for (int j = 0; j < 4; ++j) {
                    int row = ns * 16 + l16 * 4 + j;   // C/D: row=(lane>>4)*4+reg
                    mv_lds[kq][row] = minv[ns][j];
                    mi_lds[kq][row] = mini[ns][j];
                }
        }
        __syncthreads();
        if (tid < 64) {   // combine 4 quarters ascending (tie -> lower k)
            float bv = mv_lds[0][tid]; int bi = mi_lds[0][tid];
#pragma unroll
            for (int q = 1; q < 4; ++q) {
                float v = mv_lds[q][tid];
                if (v < bv) { bv = v; bi = mi_lds[q][tid]; }
            }
            ks_lds[tid] = bi;
        }
        __syncthreads();

        // r -= cb[k*]  (exact fp32, rows L2-hot)
        {
            int row = tid >> 2, dc = (tid & 3) * 16;
            int kw = ks_lds[row];
            const float* qp = cbl_g + (size_t)kw * ND + dc;
#pragma unroll
            for (int i = 0; i < 4; ++i) {
                float4 q  = *(const float4*)(qp + i * 4);
                float* rp = &r_lds[row][dc + i * 4];
                float4 rv = *(float4*)rp;
                rv.x -= q.x; rv.y -= q.y; rv.z -= q.z; rv.w -= q.w;
                *(float4*)rp = rv;
            }
        }
        __syncthreads();
    }

    // out = x - r_final
    float* ob = out + ((size_t)(b * NC + g * ND)) * NHW + n0;
#pragma unroll
    for (int dd = 0; dd < 4; ++dd) {
        int d = (tid >> 4) + dd * 16;
        int n = (tid & 15) * 4;
        float4 xv = *(const float4*)(&xb[(size_t)d * NHW + n]);
        float4 ov;
        ov.x = xv.x - r_lds[n + 0][d];
        ov.y = xv.y - r_lds[n + 1][d];
        ov.z = xv.z - r_lds[n + 2][d];
        ov.w = xv.w - r_lds[n + 3][d];
        *(float4*)(&ob[(size_t)d * NHW + n]) = ov;
    }
}

// ---------------- fallback path (round-2 kernels, 128 KB ws) ----------------
__global__ void cq_cnorm_kernel(const float* __restrict__ cb, float* __restrict__ cn) {
    int idx = blockIdx.x * 256 + threadIdx.x;
    const float4* p = reinterpret_cast<const float4*>(cb + (size_t)idx * ND);
    float s = 0.f;
#pragma unroll
    for (int i = 0; i < ND / 4; ++i) {
        float4 v = p[i];
        s += v.x * v.x + v.y * v.y + v.z * v.z + v.w * v.w;
    }
    cn[idx] = 0.5f * s;
}

__global__ __launch_bounds__(256, 1) void cq_main_kernel(
    const float* __restrict__ x, const float* __restrict__ cb,
    const float* __restrict__ cn, float* __restrict__ out)
{
    __shared__ float    r_lds[128][RS];
    __shared__ _Float16 cbh_lds[2][128][CS];
    __shared__ _Float16 cbl_lds[2][128][CS];
    __shared__ float    mv_lds[2][128];
    __shared__ int      mi_lds[2][128];
    __shared__ int      ks_lds[128];

    const int tid = threadIdx.x;
    const int blk = blockIdx.x;
    const int nt  = blk & 7;
    const int bg  = blk >> 3;
    const int g   = bg & 3;
    const int b   = bg >> 2;
    const int n0  = nt * 128;

    const float* xb = x + ((size_t)(b * NC + g * ND)) * NHW + n0;
#pragma unroll
    for (int dd = 0; dd < 8; ++dd) {
        int d = (tid >> 5) + dd * 8;
        int n = (tid & 31) * 4;
        float4 xv = *reinterpret_cast<const float4*>(&xb[(size_t)d * NHW + n]);
        r_lds[n + 0][d] = xv.x; r_lds[n + 1][d] = xv.y;
        r_lds[n + 2][d] = xv.z; r_lds[n + 3][d] = xv.w;
    }

    const int lane = tid & 63;
    const int wid  = tid >> 6;
    const int rg   = wid & 1;
    const int kh   = wid >> 1;
    const int l4   = lane & 15;
    const int l16  = lane >> 4;

    __syncthreads();

    for (int l = 0; l < NL; ++l) {
        const float* cbl_g = cb + (size_t)(l * NG + g) * NK * ND;
        const float* cnl   = cn + (size_t)(l * NG + g) * NK;

        f16x8 ah[4][2], al[4][2];
#pragma unroll
        for (int ns = 0; ns < 4; ++ns) {
#pragma unroll
            for (int c = 0; c < 2; ++c) {
                const float* rp = &r_lds[rg * 64 + ns * 16 + l4][c * 32 + l16 * 8];
                float4 v0 = *reinterpret_cast<const float4*>(rp);
                float4 v1 = *reinterpret_cast<const float4*>(rp + 4);
                _Float16 h, lo; f16x8 hv, lv;
                fsplit(-v0.x, h, lo); hv[0] = h; lv[0] = lo;
                fsplit(-v0.y, h, lo); hv[1] = h; lv[1] = lo;
                fsplit(-v0.z, h, lo); hv[2] = h; lv[2] = lo;
                fsplit(-v0.w, h, lo); hv[3] = h; lv[3] = lo;
                fsplit(-v1.x, h, lo); hv[4] = h; lv[4] = lo;
                fsplit(-v1.y, h, lo); hv[5] = h; lv[5] = lo;
                fsplit(-v1.z, h, lo); hv[6] = h; lv[6] = lo;
                fsplit(-v1.w, h, lo); hv[7] = h; lv[7] = lo;
                ah[ns][c] = hv; al[ns][c] = lv;
            }
        }

        float minv[4][4];
        int   mini[4][4];
#pragma unroll
        for (int i = 0; i < 4; ++i)
#pragma unroll
            for (int j = 0; j < 4; ++j) { minv[i][j] = 3.4e38f; mini[i][j] = 0; }

        float4 sreg[8];
#pragma unroll
        for (int p = 0; p < 8; ++p) {
            int kk = p * 16 + (tid >> 4);
            int kg = (kk < 64) ? kk : (1024 - 64 + kk);
            sreg[p] = *reinterpret_cast<const float4*>(&cbl_g[(size_t)kg * ND + (tid & 15) * 4]);
        }
#pragma unroll
        for (int p = 0; p < 8; ++p) {
            int kk = p * 16 + (tid >> 4);
            float4 v = sreg[p];
            _Float16 h, lo; f16x4 hv, lv;
            fsplit(v.x, h, lo); hv[0] = h; lv[0] = lo;
            fsplit(v.y, h, lo); hv[1] = h; lv[1] = lo;
            fsplit(v.z, h, lo); hv[2] = h; lv[2] = lo;
            fsplit(v.w, h, lo); hv[3] = h; lv[3] = lo;
            *reinterpret_cast<f16x4*>(&cbh_lds[0][kk][(tid & 15) * 4]) = hv;
            *reinterpret_cast<f16x4*>(&cbl_lds[0][kk][(tid & 15) * 4]) = lv;
        }

        for (int s = 0; s < 16; ++s) {
            __syncthreads();

            if (s < 15) {
#pragma unroll
                for (int p = 0; p < 8; ++p) {
                    int kk = p * 16 + (tid >> 4);
                    int kg = (kk < 64) ? ((s + 1) * 64 + kk) : (1024 + (s + 1) * 64 + (kk - 64));
                    sreg[p] = *reinterpret_cast<const float4*>(&cbl_g[(size_t)kg * ND + (tid & 15) * 4]);
                }
            }

            const int buf = s & 1;
            for (int ks = 0; ks < 4; ++ks) {
                int lrow = kh * 64 + ks * 16 + l4;
                int kabs = kh * 1024 + s * 64 + ks * 16 + l4;
                f16x8 bh0 = *reinterpret_cast<const f16x8*>(&cbh_lds[buf][lrow][l16 * 8]);
                f16x8 bh1 = *reinterpret_cast<const f16x8*>(&cbh_lds[buf][lrow][32 + l16 * 8]);
                f16x8 bl0 = *reinterpret_cast<const f16x8*>(&cbl_lds[buf][lrow][l16 * 8]);
                f16x8 bl1 = *reinterpret_cast<const f16x8*>(&cbl_lds[buf][lrow][32 + l16 * 8]);
                float cnv = cnl[kabs];
                f32x4 acc[4];
#pragma unroll
                for (int ns = 0; ns < 4; ++ns) acc[ns] = (f32x4){cnv, cnv, cnv, cnv};
#pragma unroll
                for (int ns = 0; ns < 4; ++ns) {
                    acc[ns] = __builtin_amdgcn_mfma_f32_16x16x32_f16(ah[ns][0], bh0, acc[ns], 0, 0, 0);
                    acc[ns] = __builtin_amdgcn_mfma_f32_16x16x32_f16(ah[ns][1], bh1, acc[ns], 0, 0, 0);
                    acc[ns] = __builtin_amdgcn_mfma_f32_16x16x32_f16(ah[ns][0], bl0, acc[ns], 0, 0, 0);
                    acc[ns] = __builtin_amdgcn_mfma_f32_16x16x32_f16(ah[ns][1], bl1, acc[ns], 0, 0, 0);
                    acc[ns] = __builtin_amdgcn_mfma_f32_16x16x32_f16(al[ns][0], bh0, acc[ns], 0, 0, 0);
                    acc[ns] = __builtin_amdgcn_mfma_f32_16x16x32_f16(al[ns][1], bh1, acc[ns], 0, 0, 0);
                }
#pragma unroll
                for (int ns = 0; ns < 4; ++ns)
#pragma unroll
                    for (int j = 0; j < 4; ++j) {
                        float sc = acc[ns][j];
                        bool lt = sc < minv[ns][j];
                        minv[ns][j] = lt ? sc : minv[ns][j];
                        mini[ns][j] = lt ? kabs : mini[ns][j];
                    }
            }

            if (s < 15) {
                const int nbuf = (s + 1) & 1;
#pragma unroll
                for (int p = 0; p < 8; ++p) {
                    int kk = p * 16 + (tid >> 4);
                    float4 v = sreg[p];
                    _Float16 h, lo; f16x4 hv, lv;
                    fsplit(v.x, h, lo); hv[0] = h; lv[0] = lo;
                    fsplit(v.y, h, lo); hv[1] = h; lv[1] = lo;
                    fsplit(v.z, h, lo); hv[2] = h; lv[2] = lo;
                    fsplit(v.w, h, lo); hv[3] = h; lv[3] = lo;
                    *reinterpret_cast<f16x4*>(&cbh_lds[nbuf][kk][(tid & 15) * 4]) = hv;
                    *reinterpret_cast<f16x4*>(&cbl_lds[nbuf][kk][(tid & 15) * 4]) = lv;
                }
            }
        }

#pragma unroll
        for (int m = 1; m < 16; m <<= 1) {
#pragma unroll
            for (int ns = 0; ns < 4; ++ns)
#pragma unroll
                for (int j = 0; j < 4; ++j) {
                    float ov = __shfl_xor(minv[ns][j], m, 64);
                    int   oi = __shfl_xor(mini[ns][j], m, 64);
                    if (ov < minv[ns][j] || (ov == minv[ns][j] && oi < mini[ns][j])) {
                        minv[ns][j] = ov; mini[ns][j] = oi;
                    }
                }
        }
        if (l4 == 0) {
#pragma unroll
            for (int ns = 0; ns < 4; ++ns)
#pragma unroll
                for (int j = 0; j < 4; ++j) {
                    int row = rg * 64 + ns * 16 + l16 * 4 + j;
                    mv_lds[kh][row] = minv[ns][j];
                    mi_lds[kh][row] = mini[ns][j];
                }
        }
        __syncthreads();
        if (tid < 128) {
            float v0 = mv_lds[0][tid], v1 = mv_lds[1][tid];
            ks_lds[tid] = (v1 < v0) ? mi_lds[1][tid] : mi_lds[0][tid];
        }
        __syncthreads();

        {
            int n  = tid >> 1;
            int db = (tid & 1) * 32;
            int kw = ks_lds[n];
            const float* qp = &cbl_g[(size_t)kw * ND + db];
#pragma unroll
            for (int i = 0; i < 8; ++i) {
                float4 q  = *reinterpret_cast<const float4*>(&qp[i * 4]);
                float* rp = &r_lds[n][db + i * 4];
                float4 rv = *reinterpret_cast<float4*>(rp);
                rv.x -= q.x; rv.y -= q.y; rv.z -= q.z; rv.w -= q.w;
                *reinterpret_cast<float4*>(rp) = rv;
            }
        }
        __syncthreads();
    }

    float* ob = out + ((size_t)(b * NC + g * ND)) * NHW + n0;
#pragma unroll
    for (int dd = 0; dd < 8; ++dd) {
        int d = (tid >> 5) + dd * 8;
        int n = (tid & 31) * 4;
        float4 xv = *reinterpret_cast<const float4*>(&xb[(size_t)d * NHW + n]);
        float4 ov;
        ov.x = xv.x - r_lds[n + 0][d];
        ov.y = xv.y - r_lds[n + 1][d];
        ov.z = xv.z - r_lds[n + 2][d];
        ov.w = xv.w - r_lds[n + 3][d];
        *reinterpret_cast<float4*>(&ob[(size_t)d * NHW + n]) = ov;
    }
}

extern "C" void kernel_launch(void* const* d_in, const int* in_sizes, int n_in,
                              void* d_out, int out_size, void* d_ws, size_t ws_size,
                              hipStream_t stream) {
    const float* x  = (const float*)d_in[0];   // [B, C, H, W]
    const float* cb = (const float*)d_in[1];   // [L, G, K, D]
    float* out = (float*)d_out;

    const size_t FRAG_BYTES = (size_t)NL * NG * NK * ND * 2 * 2;  // 8 MiB
    const size_t NEED = FRAG_BYTES + (size_t)NL * NG * NK * 4;    // + cn

    if (ws_size >= NEED) {
        _Float16* wfrag = (_Float16*)d_ws;
        float* cn = (float*)((char*)d_ws + FRAG_BYTES);
        cq_prep_kernel<<<512, 256, 0, stream>>>(cb, wfrag, cn);
        cq_main11_kernel<<<NB * NG * (NHW / 64), 256, 0, stream>>>(x, cb, wfrag, cn, out);
    } else {
        float* cn = (float*)d_ws;
        cq_cnorm_kernel<<<(NL * NG * NK) / 256, 256, 0, stream>>>(cb, cn);
        cq_main_kernel<<<NB * NG * (NHW / 128), 256, 0, stream>>>(x, cb, cn, out);
    }
}